// Round 9
// baseline (488.105 us; speedup 1.0000x reference)
//
#include <hip/hip_runtime.h>
#include <hip/hip_bf16.h>
#include <math.h>

#define NNODES 100000
#define NBMAX 512          // bucket arrays sized to 512; actual nb = ceil(N/256) = 391
#define CH 8192            // edges per partition block

typedef __hip_bfloat16 bf16;
typedef __attribute__((ext_vector_type(8))) short short8;   // bf16x8 MFMA A/B frag
typedef __attribute__((ext_vector_type(4))) float f32x4;    // MFMA C/D frag
typedef __attribute__((ext_vector_type(2))) float f32x2;

__device__ inline unsigned pack_bf16x2(float a, float b) {
    __hip_bfloat162 p;
    p.x = __float2bfloat16(a);
    p.y = __float2bfloat16(b);
    return *(unsigned*)&p;
}

__device__ inline float2 unpack_bf16x2(unsigned u) {
    __hip_bfloat162 p = *(__hip_bfloat162*)&u;
    return make_float2(__bfloat162float(p.x), __bfloat162float(p.y));
}

__device__ inline unsigned char f32_to_fp8(float v) {
    int p = __builtin_amdgcn_cvt_pk_fp8_f32(v, v, 0, false);   // OCP e4m3 on gfx950
    return (unsigned char)(p & 0xff);
}

// ---------------- weight prep (all 4) + zero-init of bcount/done/fp8 zero row ----------
__global__ __launch_bounds__(256) void prep_w_all(const float* __restrict__ W1, bf16* __restrict__ wt1,
                                                  const float* __restrict__ W2, bf16* __restrict__ wt2,
                                                  const float* __restrict__ W3, bf16* __restrict__ wt3,
                                                  const float* __restrict__ W4, bf16* __restrict__ wt4,
                                                  int* __restrict__ bcount, int* __restrict__ done,
                                                  unsigned* __restrict__ zrow) {
    int b = blockIdx.x, t = threadIdx.x;
    if (b == 0) {
        for (int i = t; i < NBMAX; i += 256) bcount[i] = 0;
        if (t == 0) *done = 0;
        if (t < 32) zrow[t] = 0u;       // 128 B fp8 zero row at h[N]
    }
    const float* W; bf16* WT; int Nout, idx0;
    if (b < 64)       { W = W1; WT = wt1; Nout = 128; idx0 = b * 256; }
    else if (b < 128) { W = W2; WT = wt2; Nout = 128; idx0 = (b - 64) * 256; }
    else if (b < 192) { W = W3; WT = wt3; Nout = 128; idx0 = (b - 128) * 256; }
    else              { W = W4; WT = wt4; Nout = 32;  idx0 = (b - 192) * 256; }
    int idx = idx0 + t;
    if (idx < 128 * Nout) {
        int nn = idx >> 7;              // K = 128 always
        int kk = idx & 127;
        WT[idx] = __float2bfloat16(W[kk * Nout + nn]);
    }
}

// ---------------- phase A+B fused: histogram, then last block scans ----------------
__global__ __launch_bounds__(256) void bucket_hist_scan(const int* __restrict__ dst,
                                                        int* __restrict__ bcount,
                                                        int* __restrict__ boff,
                                                        int* __restrict__ bcursor,
                                                        int* __restrict__ done,
                                                        int E, int nb, int nblocks) {
    __shared__ int hist[NBMAX];
    __shared__ int ticket_s;
    __shared__ int wsum[4];
    int t = threadIdx.x;
    for (int i = t; i < NBMAX; i += 256) hist[i] = 0;
    __syncthreads();
    int e0 = blockIdx.x * CH;
#pragma unroll
    for (int k = 0; k < 32; ++k) {
        int e = e0 + t + k * 256;
        if (e < E) atomicAdd(&hist[dst[e] >> 8], 1);
    }
    __syncthreads();
    for (int i = t; i < nb; i += 256)
        if (hist[i]) atomicAdd(&bcount[i], hist[i]);
    __threadfence();
    __syncthreads();
    if (t == 0) ticket_s = atomicAdd(done, 1);
    __syncthreads();
    if (ticket_s != nblocks - 1) return;    // uniform: whole block exits together
    __threadfence();
    int i0 = t * 2, i1v = t * 2 + 1;
    int a  = (i0  < nb) ? atomicAdd(&bcount[i0], 0) : 0;    // atomic read: coherent
    int bb = (i1v < nb) ? atomicAdd(&bcount[i1v], 0) : 0;
    int v = a + bb;
    int lane = t & 63, wv = t >> 6;
    int incl = v;
#pragma unroll
    for (int dd = 1; dd < 64; dd <<= 1) {
        int x = __shfl_up(incl, dd, 64);
        if (lane >= dd) incl += x;
    }
    if (lane == 63) wsum[wv] = incl;
    __syncthreads();
    int wo = 0;
    for (int k = 0; k < wv; ++k) wo += wsum[k];
    int excl = wo + incl - v;
    if (i0 <= nb)  { boff[i0]  = excl;     if (i0  < nb) bcursor[i0]  = excl; }
    if (i1v <= nb) { boff[i1v] = excl + a; if (i1v < nb) bcursor[i1v] = excl + a; }
}

// ---------------- phase C: partition edges into bucket-contiguous ranges ----------------
__global__ __launch_bounds__(256) void partition(const int* __restrict__ src,
                                                 const int* __restrict__ dst,
                                                 int* __restrict__ bcursor,
                                                 int* __restrict__ part, int E, int nb) {
    __shared__ int hist[NBMAX];
    __shared__ int cursor[NBMAX];
    int t = threadIdx.x;
    int e0 = blockIdx.x * CH;
    for (int i = t; i < NBMAX; i += 256) hist[i] = 0;
    __syncthreads();
    int mys[32], myd[32];
#pragma unroll
    for (int k = 0; k < 32; ++k) {
        int e = e0 + t + k * 256;
        int s = 0, dd = -1;
        if (e < E) { s = src[e]; dd = dst[e]; }
        mys[k] = s; myd[k] = dd;
        if (dd >= 0) atomicAdd(&hist[dd >> 8], 1);
    }
    __syncthreads();
    for (int i = t; i < nb; i += 256) {
        int c = hist[i];
        cursor[i] = c ? atomicAdd(&bcursor[i], c) : 0;   // global range reservation
    }
    __syncthreads();
#pragma unroll
    for (int k = 0; k < 32; ++k) {
        int dd = myd[k];
        if (dd >= 0) {
            int lpos = atomicAdd(&cursor[dd >> 8], 1);
            part[lpos] = mys[k] | ((dd & 255) << 24);
        }
    }
}

// ---------------- phase D+E fused: degrees -> off2[]/dinv[], then CSR fill --------------
__global__ __launch_bounds__(256) void nodes_fill(const int* __restrict__ part,
                                                  const int* __restrict__ boff,
                                                  float* __restrict__ dinv,
                                                  int2* __restrict__ off2,
                                                  int* __restrict__ edges, int n) {
    __shared__ int ndeg[256];
    __shared__ int ws2[4];
    __shared__ int offl[256];
    int b = blockIdx.x;
    int t = threadIdx.x;
    ndeg[t] = 0;
    __syncthreads();
    int r0 = boff[b], r1 = boff[b + 1];
    for (int i = r0 + t; i < r1; i += 256)
        atomicAdd(&ndeg[((unsigned)part[i]) >> 24], 1);
    __syncthreads();
    int deg = ndeg[t];
    int node = b * 256 + t;
    int lane = t & 63, wv = t >> 6;
    int incl = deg;
#pragma unroll
    for (int d = 1; d < 64; d <<= 1) {
        int x = __shfl_up(incl, d, 64);
        if (lane >= d) incl += x;
    }
    if (lane == 63) ws2[wv] = incl;
    __syncthreads();
    int wo = 0;
    for (int k = 0; k < wv; ++k) wo += ws2[k];
    int node_off = r0 + wo + incl - deg;
    if (node < n) {
        off2[node] = make_int2(node_off, node_off + deg);
        dinv[node] = rsqrtf((float)(deg + 1));     // +1: self-loop
    }
    offl[t] = node_off;
    ndeg[t] = 0;                                   // reuse as fill cursor
    __syncthreads();
    for (int i = r0 + t; i < r1; i += 256) {
        int rec = part[i];
        int dloc = ((unsigned)rec) >> 24;
        int lpos = atomicAdd(&ndeg[dloc], 1);
        edges[offl[dloc] + lpos] = rec & 0xFFFFFF;
    }
}

#define WSTRIDE 136   // bf16 elements; 272 B = 17x16 B (aligned), 2-way LDS conflict only

// ---------------- MFMA GEMM (LDS-staged WT), A fp32 [n,128] -> fp8 h' = h*dinv[row] ----
__global__ __launch_bounds__(256) void gemm128_f32A(const float* __restrict__ A,
                                                    const bf16* __restrict__ WT,
                                                    const float* __restrict__ dinv,
                                                    unsigned char* __restrict__ C, int n) {
    __shared__ bf16 wl[128 * WSTRIDE];   // 34 KB
    int t = threadIdx.x;
#pragma unroll
    for (int l = 0; l < 8; ++l) {
        int chunk = t + l * 256;           // 0..2047, 16B chunks
        int row = chunk >> 4, ch = chunk & 15;
        *(uint4*)&wl[row * WSTRIDE + ch * 8] = *(const uint4*)&WT[row * 128 + ch * 8];
    }
    __syncthreads();
    int wave = t >> 6, lane = t & 63;
    int m = lane & 15, q = lane >> 4;
    int row_base = blockIdx.x * 128 + wave * 32;
    int r0 = min(row_base + m, n - 1);
    int r1 = min(row_base + 16 + m, n - 1);

    f32x4 acc[2][8];
#pragma unroll
    for (int g = 0; g < 2; ++g)
#pragma unroll
        for (int c = 0; c < 8; ++c) acc[g][c] = (f32x4)(0.f);

#pragma unroll
    for (int kt = 0; kt < 4; ++kt) {
        short8 af[2];
#pragma unroll
        for (int g = 0; g < 2; ++g) {
            const float* ap = &A[(size_t)(g ? r1 : r0) * 128 + kt * 32 + q * 8];
            float4 f0 = *(const float4*)ap;
            float4 f1 = *(const float4*)(ap + 4);
            union { uint4 u; short8 s; } cv;
            cv.u.x = pack_bf16x2(f0.x, f0.y);
            cv.u.y = pack_bf16x2(f0.z, f0.w);
            cv.u.z = pack_bf16x2(f1.x, f1.y);
            cv.u.w = pack_bf16x2(f1.z, f1.w);
            af[g] = cv.s;
        }
#pragma unroll
        for (int c = 0; c < 8; ++c) {
            short8 bf = *(const short8*)&wl[(c * 16 + m) * WSTRIDE + kt * 32 + q * 8];
            acc[0][c] = __builtin_amdgcn_mfma_f32_16x16x32_bf16(af[0], bf, acc[0][c], 0, 0, 0);
            acc[1][c] = __builtin_amdgcn_mfma_f32_16x16x32_bf16(af[1], bf, acc[1][c], 0, 0, 0);
        }
    }
    float dv[2][4];
#pragma unroll
    for (int g = 0; g < 2; ++g)
#pragma unroll
        for (int r = 0; r < 4; ++r) {
            int row = row_base + g * 16 + q * 4 + r;
            dv[g][r] = (row < n) ? dinv[row] : 0.f;
        }
#pragma unroll
    for (int g = 0; g < 2; ++g)
#pragma unroll
        for (int c = 0; c < 8; ++c)
#pragma unroll
            for (int r = 0; r < 4; ++r) {
                int row = row_base + g * 16 + q * 4 + r;
                if (row < n) C[(size_t)row * 128 + c * 16 + m] = f32_to_fp8(acc[g][c][r] * dv[g][r]);
            }
}

// ---------------- MFMA GEMM (LDS-staged WT), A bf16 [n,128] -> fp8 h' ----------------
__global__ __launch_bounds__(256) void gemm128_bf16A(const bf16* __restrict__ A,
                                                     const bf16* __restrict__ WT,
                                                     const float* __restrict__ dinv,
                                                     unsigned char* __restrict__ C, int n) {
    __shared__ bf16 wl[128 * WSTRIDE];   // 34 KB
    int t = threadIdx.x;
#pragma unroll
    for (int l = 0; l < 8; ++l) {
        int chunk = t + l * 256;
        int row = chunk >> 4, ch = chunk & 15;
        *(uint4*)&wl[row * WSTRIDE + ch * 8] = *(const uint4*)&WT[row * 128 + ch * 8];
    }
    __syncthreads();
    int wave = t >> 6, lane = t & 63;
    int m = lane & 15, q = lane >> 4;
    int row_base = blockIdx.x * 128 + wave * 32;
    int r0 = min(row_base + m, n - 1);
    int r1 = min(row_base + 16 + m, n - 1);

    f32x4 acc[2][8];
#pragma unroll
    for (int g = 0; g < 2; ++g)
#pragma unroll
        for (int c = 0; c < 8; ++c) acc[g][c] = (f32x4)(0.f);

#pragma unroll
    for (int kt = 0; kt < 4; ++kt) {
        short8 a0 = *(const short8*)&A[(size_t)r0 * 128 + kt * 32 + q * 8];
        short8 a1 = *(const short8*)&A[(size_t)r1 * 128 + kt * 32 + q * 8];
#pragma unroll
        for (int c = 0; c < 8; ++c) {
            short8 bf = *(const short8*)&wl[(c * 16 + m) * WSTRIDE + kt * 32 + q * 8];
            acc[0][c] = __builtin_amdgcn_mfma_f32_16x16x32_bf16(a0, bf, acc[0][c], 0, 0, 0);
            acc[1][c] = __builtin_amdgcn_mfma_f32_16x16x32_bf16(a1, bf, acc[1][c], 0, 0, 0);
        }
    }
    float dv[2][4];
#pragma unroll
    for (int g = 0; g < 2; ++g)
#pragma unroll
        for (int r = 0; r < 4; ++r) {
            int row = row_base + g * 16 + q * 4 + r;
            dv[g][r] = (row < n) ? dinv[row] : 0.f;
        }
#pragma unroll
    for (int g = 0; g < 2; ++g)
#pragma unroll
        for (int c = 0; c < 8; ++c)
#pragma unroll
            for (int r = 0; r < 4; ++r) {
                int row = row_base + g * 16 + q * 4 + r;
                if (row < n) C[(size_t)row * 128 + c * 16 + m] = f32_to_fp8(acc[g][c][r] * dv[g][r]);
            }
}

// ---------------- MFMA GEMM, A bf16 [n,128] x WT4 [32][128] -> bf16 h'4 = h4*dinv ------
// Block 0 also zeroes the bf16 zero row at C[n*32 .. n*32+32) for agg32's tail clamp.
__global__ __launch_bounds__(256) void gemm32_bf16A(const bf16* __restrict__ A,
                                                    const bf16* __restrict__ WT,
                                                    const float* __restrict__ dinv,
                                                    bf16* __restrict__ C, int n) {
    if (blockIdx.x == 0 && threadIdx.x < 32)
        C[(size_t)n * 32 + threadIdx.x] = __float2bfloat16(0.f);
    int wave = threadIdx.x >> 6;
    int lane = threadIdx.x & 63;
    int m = lane & 15;
    int q = lane >> 4;
    int row_base = blockIdx.x * 64 + wave * 16;
    int arow = min(row_base + m, n - 1);

    f32x4 acc[2];
    acc[0] = (f32x4)(0.f);
    acc[1] = (f32x4)(0.f);

#pragma unroll
    for (int kt = 0; kt < 4; ++kt) {
        short8 af = *(const short8*)&A[(size_t)arow * 128 + kt * 32 + q * 8];
#pragma unroll
        for (int c = 0; c < 2; ++c) {
            short8 bf = *(const short8*)&WT[(size_t)(c * 16 + m) * 128 + kt * 32 + q * 8];
            acc[c] = __builtin_amdgcn_mfma_f32_16x16x32_bf16(af, bf, acc[c], 0, 0, 0);
        }
    }
    float dv[4];
#pragma unroll
    for (int r = 0; r < 4; ++r) {
        int row = row_base + q * 4 + r;
        dv[r] = (row < n) ? dinv[row] : 0.f;
    }
#pragma unroll
    for (int c = 0; c < 2; ++c)
#pragma unroll
        for (int r = 0; r < 4; ++r) {
            int row = row_base + q * 4 + r;
            if (row < n) C[(size_t)row * 32 + c * 16 + m] = __float2bfloat16(acc[c][r] * dv[r]);
        }
}

// ---------------- aggregation F=128 fp8: dwordx4 gathers, 8 edges/instr ----------------
// R6-proven structure (58 us full-range). Range [n0,n1) per dispatch: split into two
// half dispatches to lower the rocprof top-5 cutoff (~29 us) and reveal hidden kernels.
__global__ __launch_bounds__(256) void agg128(const unsigned char* __restrict__ h,
                                              const int2* __restrict__ off2,
                                              const int* __restrict__ edges,
                                              const float* __restrict__ dinv,
                                              const float* __restrict__ bias,
                                              bf16* __restrict__ out, int n,
                                              int n0, int n1) {
    int wid = n0 + ((blockIdx.x * blockDim.x + threadIdx.x) >> 6);
    if (wid >= n1) return;
    int lane = threadIdx.x & 63;
    int g = lane >> 3;                 // edge slot within a gather (0..7)
    int d = lane & 7;                  // 16 B chunk of row
    int l32 = lane & 31;               // position within a 32-edge index window
    const char* hb = (const char*)h;
    unsigned doff = (unsigned)(d << 4);

    int2 rng = off2[wid];
    int i0 = rng.x, i1 = rng.y;
    int deg = i1 - i0;
    int rem = deg & 31;
    int tail = i1 - rem;

    // tail index window: one coalesced load, OOB lanes clamped to zero row h[n]
    int tw = n;
    if (rem) {
        int te = edges[tail + l32];    // slack-allocated
        tw = (l32 < rem) ? te : n;
    }

    f32x2 A[8];
#pragma unroll
    for (int q = 0; q < 8; ++q) A[q] = (f32x2){0.f, 0.f};

    if (g == 0) {                      // self-loop: slot 0 only (8 lanes cover the row)
        uint4 su = *(const uint4*)(hb + (((unsigned)wid << 7) | doff));
        A[0] += __builtin_amdgcn_cvt_pk_f32_fp8((int)su.x, false);
        A[1] += __builtin_amdgcn_cvt_pk_f32_fp8((int)su.x, true);
        A[2] += __builtin_amdgcn_cvt_pk_f32_fp8((int)su.y, false);
        A[3] += __builtin_amdgcn_cvt_pk_f32_fp8((int)su.y, true);
        A[4] += __builtin_amdgcn_cvt_pk_f32_fp8((int)su.z, false);
        A[5] += __builtin_amdgcn_cvt_pk_f32_fp8((int)su.z, true);
        A[6] += __builtin_amdgcn_cvt_pk_f32_fp8((int)su.w, false);
        A[7] += __builtin_amdgcn_cvt_pk_f32_fp8((int)su.w, true);
    }

    int i = i0;
    int ew;
    if (i + 32 <= i1) ew = edges[i + l32];
    while (i + 32 <= i1) {             // full 32-edge chunks: 4 gathers of 8 edges
        int idxs[4];
#pragma unroll
        for (int j = 0; j < 4; ++j) idxs[j] = __shfl(ew, j * 8 + g, 64);
        uint4 uu[4];
#pragma unroll
        for (int j = 0; j < 4; ++j)
            uu[j] = *(const uint4*)(hb + (((unsigned)idxs[j] << 7) | doff));
        int inext = i + 32;
        if (inext + 32 <= i1) ew = edges[inext + l32];   // prefetch next window
#pragma unroll
        for (int j = 0; j < 4; ++j) {
            A[0] += __builtin_amdgcn_cvt_pk_f32_fp8((int)uu[j].x, false);
            A[1] += __builtin_amdgcn_cvt_pk_f32_fp8((int)uu[j].x, true);
            A[2] += __builtin_amdgcn_cvt_pk_f32_fp8((int)uu[j].y, false);
            A[3] += __builtin_amdgcn_cvt_pk_f32_fp8((int)uu[j].y, true);
            A[4] += __builtin_amdgcn_cvt_pk_f32_fp8((int)uu[j].z, false);
            A[5] += __builtin_amdgcn_cvt_pk_f32_fp8((int)uu[j].z, true);
            A[6] += __builtin_amdgcn_cvt_pk_f32_fp8((int)uu[j].w, false);
            A[7] += __builtin_amdgcn_cvt_pk_f32_fp8((int)uu[j].w, true);
        }
        i = inext;
    }
    if (rem) {                         // tail: predicated groups of 8, window pre-clamped
        int njg = (rem + 7) >> 3;      // 1..4
        int idxs[4];
        uint4 uu[4];
#pragma unroll
        for (int j = 0; j < 4; ++j)
            if (j < njg) idxs[j] = __shfl(tw, j * 8 + g, 64);
#pragma unroll
        for (int j = 0; j < 4; ++j)
            if (j < njg) uu[j] = *(const uint4*)(hb + (((unsigned)idxs[j] << 7) | doff));
#pragma unroll
        for (int j = 0; j < 4; ++j) {
            if (j < njg) {
                A[0] += __builtin_amdgcn_cvt_pk_f32_fp8((int)uu[j].x, false);
                A[1] += __builtin_amdgcn_cvt_pk_f32_fp8((int)uu[j].x, true);
                A[2] += __builtin_amdgcn_cvt_pk_f32_fp8((int)uu[j].y, false);
                A[3] += __builtin_amdgcn_cvt_pk_f32_fp8((int)uu[j].y, true);
                A[4] += __builtin_amdgcn_cvt_pk_f32_fp8((int)uu[j].z, false);
                A[5] += __builtin_amdgcn_cvt_pk_f32_fp8((int)uu[j].z, true);
                A[6] += __builtin_amdgcn_cvt_pk_f32_fp8((int)uu[j].w, false);
                A[7] += __builtin_amdgcn_cvt_pk_f32_fp8((int)uu[j].w, true);
            }
        }
    }
    // 3-stage specializing butterfly across the 8 edge slots (g bits at lane 3,4,5)
    bool k0 = (g & 1) != 0, k1 = (g & 2) != 0, k2 = (g & 4) != 0;
    f32x2 B1[4];
#pragma unroll
    for (int q = 0; q < 4; ++q) {
        f32x2 K = k0 ? A[q + 4] : A[q];
        f32x2 S = k0 ? A[q] : A[q + 4];
        f32x2 R; R[0] = __shfl_xor(S[0], 8, 64); R[1] = __shfl_xor(S[1], 8, 64);
        B1[q] = K + R;
    }
    f32x2 B2[2];
#pragma unroll
    for (int q = 0; q < 2; ++q) {
        f32x2 K = k1 ? B1[q + 2] : B1[q];
        f32x2 S = k1 ? B1[q] : B1[q + 2];
        f32x2 R; R[0] = __shfl_xor(S[0], 16, 64); R[1] = __shfl_xor(S[1], 16, 64);
        B2[q] = K + R;
    }
    f32x2 K3 = k2 ? B2[1] : B2[0];
    f32x2 S3 = k2 ? B2[0] : B2[1];
    f32x2 R3; R3[0] = __shfl_xor(S3[0], 32, 64); R3[1] = __shfl_xor(S3[1], 32, 64);
    f32x2 F = K3 + R3;

    int od = d * 8 + (k0 ? 4 : 0) + (k1 ? 2 : 0) + (k2 ? 1 : 0);
    float dl = dinv[wid];
    float2 bv = *(const float2*)&bias[od * 2];
    float a0 = fmaxf(F[0] * dl + bv.x, 0.f);
    float a1 = fmaxf(F[1] * dl + bv.y, 0.f);
    ((unsigned*)out)[(size_t)wid * 64 + od] = pack_bf16x2(a0, a1);
}

// ---------------- aggregation F=32 bf16: window+shuffle + log_softmax -> fp32 ----------
// Half-wave per node. lane5 = (g,d): g = edge slot (0..3), d = 8 B chunk.
// Shuffle sources stay within the node's 32-lane half (halfbase = lane & 32).
__global__ __launch_bounds__(256) void agg32_lsm(const bf16* __restrict__ h,
                                                 const int2* __restrict__ off2,
                                                 const int* __restrict__ edges,
                                                 const float* __restrict__ dinv,
                                                 const float* __restrict__ bias,
                                                 float* __restrict__ out, int n) {
    int idx = blockIdx.x * blockDim.x + threadIdx.x;
    int node = idx >> 5;
    if (node >= n) return;
    int lane = threadIdx.x & 63;
    int halfbase = lane & 32;
    int lane5 = lane & 31;
    int g = lane5 >> 3;        // edge slot 0..3
    int d = lane5 & 7;         // features d*4 .. d*4+3 (8 B = 4 bf16)
    int l16 = lane5 & 15;      // position within a 16-edge index window
    const char* hb = (const char*)h;
    unsigned doff = (unsigned)(d << 3);

    int2 rng = off2[node];
    int i0 = rng.x, i1 = rng.y;
    int deg = i1 - i0;
    int rem = deg & 15;
    int tail = i1 - rem;

    int tw = n;
    if (rem) {
        int te = edges[tail + l16];
        tw = (l16 < rem) ? te : n;    // bf16 zero row at h[n] (written by gemm32)
    }

    f32x2 acc0 = {0.f, 0.f}, acc1 = {0.f, 0.f};
    {   // self-loop: slot 0 only
        uint2 su = *(const uint2*)(hb + (((unsigned)node << 6) | doff));
        if (g) { su.x = 0u; su.y = 0u; }
        float2 f0 = unpack_bf16x2(su.x), f1 = unpack_bf16x2(su.y);
        acc0[0] += f0.x; acc0[1] += f0.y; acc1[0] += f1.x; acc1[1] += f1.y;
    }
    int i = i0;
    int ew;
    if (i + 16 <= i1) ew = edges[i + l16];
    while (i + 16 <= i1) {             // full 16-edge chunks
        int idxs[4];
#pragma unroll
        for (int j = 0; j < 4; ++j) idxs[j] = __shfl(ew, halfbase + j * 4 + g, 64);
        uint2 uu[4];
#pragma unroll
        for (int j = 0; j < 4; ++j)
            uu[j] = *(const uint2*)(hb + (((unsigned)idxs[j] << 6) | doff));
        int inext = i + 16;
        if (inext + 16 <= i1) ew = edges[inext + l16];
#pragma unroll
        for (int j = 0; j < 4; ++j) {
            float2 f0 = unpack_bf16x2(uu[j].x), f1 = unpack_bf16x2(uu[j].y);
            acc0[0] += f0.x; acc0[1] += f0.y; acc1[0] += f1.x; acc1[1] += f1.y;
        }
        i = inext;
    }
    if (rem) {                         // tail: predicated, window pre-clamped
        int njg = (rem + 3) >> 2;      // 1..4
        int idxs[4];
        uint2 uu[4];
#pragma unroll
        for (int j = 0; j < 4; ++j)
            if (j < njg) idxs[j] = __shfl(tw, halfbase + j * 4 + g, 64);
#pragma unroll
        for (int j = 0; j < 4; ++j)
            if (j < njg) uu[j] = *(const uint2*)(hb + (((unsigned)idxs[j] << 6) | doff));
#pragma unroll
        for (int j = 0; j < 4; ++j) {
            if (j < njg) {
                float2 f0 = unpack_bf16x2(uu[j].x), f1 = unpack_bf16x2(uu[j].y);
                acc0[0] += f0.x; acc0[1] += f0.y; acc1[0] += f1.x; acc1[1] += f1.y;
            }
        }
    }
    // reduce across edge slots: g bits are lane bits 3,4 (within the 32-lane half)
    float s0 = acc0[0], s1 = acc0[1], s2 = acc1[0], s3 = acc1[1];
    s0 += __shfl_xor(s0, 8);  s1 += __shfl_xor(s1, 8);
    s2 += __shfl_xor(s2, 8);  s3 += __shfl_xor(s3, 8);
    s0 += __shfl_xor(s0, 16); s1 += __shfl_xor(s1, 16);
    s2 += __shfl_xor(s2, 16); s3 += __shfl_xor(s3, 16);

    float dl = dinv[node];
    float4 bv = *(const float4*)&bias[d * 4];
    float a0 = s0 * dl + bv.x;
    float a1 = s1 * dl + bv.y;
    float a2 = s2 * dl + bv.z;
    float a3 = s3 * dl + bv.w;
    // log_softmax over 32 features: 4 in-lane + across d lanes (bits 0..2)
    float m = fmaxf(fmaxf(a0, a1), fmaxf(a2, a3));
    for (int dd = 1; dd < 8; dd <<= 1) m = fmaxf(m, __shfl_xor(m, dd));
    float e = expf(a0 - m) + expf(a1 - m) + expf(a2 - m) + expf(a3 - m);
    for (int dd = 1; dd < 8; dd <<= 1) e += __shfl_xor(e, dd);
    float lse = m + logf(e);
    if (g == 0)
        *(float4*)&out[(size_t)node * 32 + d * 4] =
            make_float4(a0 - lse, a1 - lse, a2 - lse, a3 - lse);
}

extern "C" void kernel_launch(void* const* d_in, const int* in_sizes, int n_in,
                              void* d_out, int out_size, void* d_ws, size_t ws_size,
                              hipStream_t stream) {
    const float* x  = (const float*)d_in[0];
    const int*   ei = (const int*)d_in[1];
    const float* W1 = (const float*)d_in[2];
    const float* b1 = (const float*)d_in[3];
    const float* W2 = (const float*)d_in[4];
    const float* b2 = (const float*)d_in[5];
    const float* W3 = (const float*)d_in[6];
    const float* b3 = (const float*)d_in[7];
    const float* W4 = (const float*)d_in[8];
    const float* b4 = (const float*)d_in[9];
    float* out = (float*)d_out;

    const int N = NNODES;
    const int E = in_sizes[1] / 2;
    const int nb = (N + 255) / 256;           // 391 buckets

    char* ws = (char*)d_ws;
    size_t o = 0;
    auto alloc = [&](size_t bytes) -> void* {
        void* p = ws + o;
        o += (bytes + 255) & ~(size_t)255;
        return p;
    };
    int*   bcount  = (int*)alloc((size_t)NBMAX * 4);
    int*   boff    = (int*)alloc((size_t)(NBMAX + 1) * 4);
    int*   bcursor = (int*)alloc((size_t)NBMAX * 4);
    int*   done    = (int*)alloc(4);
    int2*  off2    = (int2*)alloc((size_t)N * 8);
    float* dinv    = (float*)alloc((size_t)N * 4);
    int*   part    = (int*)alloc((size_t)E * 8);       // packed ints; region sized E*8 so
                                                       // it can alias gbuf (N*256 B) below
    int*   edges   = (int*)alloc((size_t)(E + 64) * 4); // +64 slack for tail-window reads
    bf16*  wt1     = (bf16*)alloc((size_t)128 * 128 * 2);
    bf16*  wt2     = (bf16*)alloc((size_t)128 * 128 * 2);
    bf16*  wt3     = (bf16*)alloc((size_t)128 * 128 * 2);
    bf16*  wt4     = (bf16*)alloc((size_t)32 * 128 * 2);
    unsigned char* hbuf = (unsigned char*)alloc((size_t)(N + 1) * 128);  // +1: zero row
    bf16*  gbuf    = (bf16*)part;              // part dead after nodes_fill; N*256B == E*8B

    const int* srcv = ei;
    const int* dstv = ei + E;

    int pblocks = (E + CH - 1) / CH;

    // prep_w_all also zeroes bcount/done/fp8-zero-row -> no memsets, runs first
    prep_w_all<<<208, 256, 0, stream>>>(W1, wt1, W2, wt2, W3, wt3, W4, wt4,
                                        bcount, done, (unsigned*)(hbuf + (size_t)N * 128));
    bucket_hist_scan<<<pblocks, 256, 0, stream>>>(dstv, bcount, boff, bcursor, done,
                                                  E, nb, pblocks);
    partition<<<pblocks, 256, 0, stream>>>(srcv, dstv, bcursor, part, E, nb);
    nodes_fill<<<nb, 256, 0, stream>>>(part, boff, dinv, off2, edges, N);

    int gemm128_blocks = (N + 127) / 128;
    int gemm32_blocks = (N + 63) / 64;
    int half = N / 2;                          // N even
    int aggh_blocks = (half + 3) / 4;          // 4 waves/block, 1 node/wave
    int agg32_blocks = (N * 32 + 255) / 256;

    // Layer 1 (A fp32) -> fp8 h' (pre-scaled by dinv); agg in two half-range dispatches
    gemm128_f32A<<<gemm128_blocks, 256, 0, stream>>>(x, wt1, dinv, hbuf, N);
    agg128<<<aggh_blocks, 256, 0, stream>>>(hbuf, off2, edges, dinv, b1, gbuf, N, 0, half);
    agg128<<<aggh_blocks, 256, 0, stream>>>(hbuf, off2, edges, dinv, b1, gbuf, N, half, N);
    // Layer 2
    gemm128_bf16A<<<gemm128_blocks, 256, 0, stream>>>(gbuf, wt2, dinv, hbuf, N);
    agg128<<<aggh_blocks, 256, 0, stream>>>(hbuf, off2, edges, dinv, b2, gbuf, N, 0, half);
    agg128<<<aggh_blocks, 256, 0, stream>>>(hbuf, off2, edges, dinv, b2, gbuf, N, half, N);
    // Layer 3
    gemm128_bf16A<<<gemm128_blocks, 256, 0, stream>>>(gbuf, wt3, dinv, hbuf, N);
    agg128<<<aggh_blocks, 256, 0, stream>>>(hbuf, off2, edges, dinv, b3, gbuf, N, 0, half);
    agg128<<<aggh_blocks, 256, 0, stream>>>(hbuf, off2, edges, dinv, b3, gbuf, N, half, N);
    // Layer 4: GEMM to 32 cols (bf16 h'4 - protect final logits), then agg + log_softmax
    gemm32_bf16A<<<gemm32_blocks, 256, 0, stream>>>(gbuf, wt4, dinv, (bf16*)hbuf, N);
    agg32_lsm<<<agg32_blocks, 256, 0, stream>>>((const bf16*)hbuf, off2, edges, dinv, b4, out, N);
}

// Round 10
// 459.683 us; speedup vs baseline: 1.0618x; 1.0618x over previous
//
#include <hip/hip_runtime.h>
#include <hip/hip_bf16.h>
#include <math.h>

#define NNODES 100000
#define NBMAX 512          // bucket arrays sized to 512; actual nb = ceil(N/256) = 391
#define CH 8192            // edges per partition block

typedef __hip_bfloat16 bf16;
typedef __attribute__((ext_vector_type(8))) short short8;   // bf16x8 MFMA A/B frag
typedef __attribute__((ext_vector_type(4))) float f32x4;    // MFMA C/D frag
typedef __attribute__((ext_vector_type(2))) float f32x2;

__device__ inline unsigned pack_bf16x2(float a, float b) {
    __hip_bfloat162 p;
    p.x = __float2bfloat16(a);
    p.y = __float2bfloat16(b);
    return *(unsigned*)&p;
}

__device__ inline float2 unpack_bf16x2(unsigned u) {
    __hip_bfloat162 p = *(__hip_bfloat162*)&u;
    return make_float2(__bfloat162float(p.x), __bfloat162float(p.y));
}

__device__ inline unsigned char f32_to_fp8(float v) {
    int p = __builtin_amdgcn_cvt_pk_fp8_f32(v, v, 0, false);   // OCP e4m3 on gfx950
    return (unsigned char)(p & 0xff);
}

// ---------------- weight prep (all 4) + zero-init of bcount/done/fp8 zero row ----------
__global__ __launch_bounds__(256) void prep_w_all(const float* __restrict__ W1, bf16* __restrict__ wt1,
                                                  const float* __restrict__ W2, bf16* __restrict__ wt2,
                                                  const float* __restrict__ W3, bf16* __restrict__ wt3,
                                                  const float* __restrict__ W4, bf16* __restrict__ wt4,
                                                  int* __restrict__ bcount, int* __restrict__ done,
                                                  unsigned* __restrict__ zrow) {
    int b = blockIdx.x, t = threadIdx.x;
    if (b == 0) {
        for (int i = t; i < NBMAX; i += 256) bcount[i] = 0;
        if (t == 0) *done = 0;
        if (t < 32) zrow[t] = 0u;       // 128 B fp8 zero row at h[N]
    }
    const float* W; bf16* WT; int Nout, idx0;
    if (b < 64)       { W = W1; WT = wt1; Nout = 128; idx0 = b * 256; }
    else if (b < 128) { W = W2; WT = wt2; Nout = 128; idx0 = (b - 64) * 256; }
    else if (b < 192) { W = W3; WT = wt3; Nout = 128; idx0 = (b - 128) * 256; }
    else              { W = W4; WT = wt4; Nout = 32;  idx0 = (b - 192) * 256; }
    int idx = idx0 + t;
    if (idx < 128 * Nout) {
        int nn = idx >> 7;              // K = 128 always
        int kk = idx & 127;
        WT[idx] = __float2bfloat16(W[kk * Nout + nn]);
    }
}

// ---------------- phase A+B fused: histogram, then last block scans ----------------
// Loads batched into registers BEFORE the LDS atomics: R9 showed VGPR=8 => serialized
// load->atomic->load latency chain (44 us, VALUBusy 1.2%). myb[32] forces all 32 loads
// in flight (partition's proven pattern).
__global__ __launch_bounds__(256) void bucket_hist_scan(const int* __restrict__ dst,
                                                        int* __restrict__ bcount,
                                                        int* __restrict__ boff,
                                                        int* __restrict__ bcursor,
                                                        int* __restrict__ done,
                                                        int E, int nb, int nblocks) {
    __shared__ int hist[NBMAX];
    __shared__ int ticket_s;
    __shared__ int wsum[4];
    int t = threadIdx.x;
    for (int i = t; i < NBMAX; i += 256) hist[i] = 0;
    __syncthreads();
    int e0 = blockIdx.x * CH;
    int myb[32];
#pragma unroll
    for (int k = 0; k < 32; ++k) {
        int e = e0 + t + k * 256;
        myb[k] = (e < E) ? (dst[e] >> 8) : -1;
    }
#pragma unroll
    for (int k = 0; k < 32; ++k)
        if (myb[k] >= 0) atomicAdd(&hist[myb[k]], 1);
    __syncthreads();
    for (int i = t; i < nb; i += 256)
        if (hist[i]) atomicAdd(&bcount[i], hist[i]);
    __threadfence();
    __syncthreads();
    if (t == 0) ticket_s = atomicAdd(done, 1);
    __syncthreads();
    if (ticket_s != nblocks - 1) return;    // uniform: whole block exits together
    __threadfence();
    int i0 = t * 2, i1v = t * 2 + 1;
    int a  = (i0  < nb) ? atomicAdd(&bcount[i0], 0) : 0;    // atomic read: coherent
    int bb = (i1v < nb) ? atomicAdd(&bcount[i1v], 0) : 0;
    int v = a + bb;
    int lane = t & 63, wv = t >> 6;
    int incl = v;
#pragma unroll
    for (int dd = 1; dd < 64; dd <<= 1) {
        int x = __shfl_up(incl, dd, 64);
        if (lane >= dd) incl += x;
    }
    if (lane == 63) wsum[wv] = incl;
    __syncthreads();
    int wo = 0;
    for (int k = 0; k < wv; ++k) wo += wsum[k];
    int excl = wo + incl - v;
    if (i0 <= nb)  { boff[i0]  = excl;     if (i0  < nb) bcursor[i0]  = excl; }
    if (i1v <= nb) { boff[i1v] = excl + a; if (i1v < nb) bcursor[i1v] = excl + a; }
}

// ---------------- phase C: partition edges into bucket-contiguous ranges ----------------
// Atomic phase split from the load phase (loads fully batched first).
__global__ __launch_bounds__(256) void partition(const int* __restrict__ src,
                                                 const int* __restrict__ dst,
                                                 int* __restrict__ bcursor,
                                                 int* __restrict__ part, int E, int nb) {
    __shared__ int hist[NBMAX];
    __shared__ int cursor[NBMAX];
    int t = threadIdx.x;
    int e0 = blockIdx.x * CH;
    for (int i = t; i < NBMAX; i += 256) hist[i] = 0;
    __syncthreads();
    int mys[32], myd[32];
#pragma unroll
    for (int k = 0; k < 32; ++k) {
        int e = e0 + t + k * 256;
        int s = 0, dd = -1;
        if (e < E) { s = src[e]; dd = dst[e]; }
        mys[k] = s; myd[k] = dd;
    }
#pragma unroll
    for (int k = 0; k < 32; ++k)
        if (myd[k] >= 0) atomicAdd(&hist[myd[k] >> 8], 1);
    __syncthreads();
    for (int i = t; i < nb; i += 256) {
        int c = hist[i];
        cursor[i] = c ? atomicAdd(&bcursor[i], c) : 0;   // global range reservation
    }
    __syncthreads();
#pragma unroll
    for (int k = 0; k < 32; ++k) {
        int dd = myd[k];
        if (dd >= 0) {
            int lpos = atomicAdd(&cursor[dd >> 8], 1);
            part[lpos] = mys[k] | ((dd & 255) << 24);
        }
    }
}

// ---------------- phase D+E fused: degrees -> off2[]/dinv[], then CSR fill --------------
// Both passes over part[] batch 8 loads into registers before the LDS atomics.
__global__ __launch_bounds__(256) void nodes_fill(const int* __restrict__ part,
                                                  const int* __restrict__ boff,
                                                  float* __restrict__ dinv,
                                                  int2* __restrict__ off2,
                                                  int* __restrict__ edges, int n) {
    __shared__ int ndeg[256];
    __shared__ int ws2[4];
    __shared__ int offl[256];
    int b = blockIdx.x;
    int t = threadIdx.x;
    ndeg[t] = 0;
    __syncthreads();
    int r0 = boff[b], r1 = boff[b + 1];
    for (int i = r0 + t; i < r1; i += 256 * 8) {
        int v[8];
#pragma unroll
        for (int j = 0; j < 8; ++j) {
            int idx = i + j * 256;
            v[j] = (idx < r1) ? (int)(((unsigned)part[idx]) >> 24) : -1;
        }
#pragma unroll
        for (int j = 0; j < 8; ++j)
            if (v[j] >= 0) atomicAdd(&ndeg[v[j]], 1);
    }
    __syncthreads();
    int deg = ndeg[t];
    int node = b * 256 + t;
    int lane = t & 63, wv = t >> 6;
    int incl = deg;
#pragma unroll
    for (int d = 1; d < 64; d <<= 1) {
        int x = __shfl_up(incl, d, 64);
        if (lane >= d) incl += x;
    }
    if (lane == 63) ws2[wv] = incl;
    __syncthreads();
    int wo = 0;
    for (int k = 0; k < wv; ++k) wo += ws2[k];
    int node_off = r0 + wo + incl - deg;
    if (node < n) {
        off2[node] = make_int2(node_off, node_off + deg);
        dinv[node] = rsqrtf((float)(deg + 1));     // +1: self-loop
    }
    offl[t] = node_off;
    ndeg[t] = 0;                                   // reuse as fill cursor
    __syncthreads();
    for (int i = r0 + t; i < r1; i += 256 * 8) {
        int rec[8];
#pragma unroll
        for (int j = 0; j < 8; ++j) {
            int idx = i + j * 256;
            if (idx < r1) rec[j] = part[idx];
        }
#pragma unroll
        for (int j = 0; j < 8; ++j) {
            if (i + j * 256 < r1) {
                int dloc = ((unsigned)rec[j]) >> 24;
                int lpos = atomicAdd(&ndeg[dloc], 1);
                edges[offl[dloc] + lpos] = rec[j] & 0xFFFFFF;
            }
        }
    }
}

#define WSTRIDE 136   // bf16 elements; 272 B = 17x16 B (aligned), 2-way LDS conflict only

// ---------------- MFMA GEMM (LDS-staged WT), A fp32 [n,128] -> fp8 h' = h*dinv[row] ----
__global__ __launch_bounds__(256) void gemm128_f32A(const float* __restrict__ A,
                                                    const bf16* __restrict__ WT,
                                                    const float* __restrict__ dinv,
                                                    unsigned char* __restrict__ C, int n) {
    __shared__ bf16 wl[128 * WSTRIDE];   // 34 KB
    int t = threadIdx.x;
#pragma unroll
    for (int l = 0; l < 8; ++l) {
        int chunk = t + l * 256;           // 0..2047, 16B chunks
        int row = chunk >> 4, ch = chunk & 15;
        *(uint4*)&wl[row * WSTRIDE + ch * 8] = *(const uint4*)&WT[row * 128 + ch * 8];
    }
    __syncthreads();
    int wave = t >> 6, lane = t & 63;
    int m = lane & 15, q = lane >> 4;
    int row_base = blockIdx.x * 128 + wave * 32;
    int r0 = min(row_base + m, n - 1);
    int r1 = min(row_base + 16 + m, n - 1);

    f32x4 acc[2][8];
#pragma unroll
    for (int g = 0; g < 2; ++g)
#pragma unroll
        for (int c = 0; c < 8; ++c) acc[g][c] = (f32x4)(0.f);

#pragma unroll
    for (int kt = 0; kt < 4; ++kt) {
        short8 af[2];
#pragma unroll
        for (int g = 0; g < 2; ++g) {
            const float* ap = &A[(size_t)(g ? r1 : r0) * 128 + kt * 32 + q * 8];
            float4 f0 = *(const float4*)ap;
            float4 f1 = *(const float4*)(ap + 4);
            union { uint4 u; short8 s; } cv;
            cv.u.x = pack_bf16x2(f0.x, f0.y);
            cv.u.y = pack_bf16x2(f0.z, f0.w);
            cv.u.z = pack_bf16x2(f1.x, f1.y);
            cv.u.w = pack_bf16x2(f1.z, f1.w);
            af[g] = cv.s;
        }
#pragma unroll
        for (int c = 0; c < 8; ++c) {
            short8 bf = *(const short8*)&wl[(c * 16 + m) * WSTRIDE + kt * 32 + q * 8];
            acc[0][c] = __builtin_amdgcn_mfma_f32_16x16x32_bf16(af[0], bf, acc[0][c], 0, 0, 0);
            acc[1][c] = __builtin_amdgcn_mfma_f32_16x16x32_bf16(af[1], bf, acc[1][c], 0, 0, 0);
        }
    }
    float dv[2][4];
#pragma unroll
    for (int g = 0; g < 2; ++g)
#pragma unroll
        for (int r = 0; r < 4; ++r) {
            int row = row_base + g * 16 + q * 4 + r;
            dv[g][r] = (row < n) ? dinv[row] : 0.f;
        }
#pragma unroll
    for (int g = 0; g < 2; ++g)
#pragma unroll
        for (int c = 0; c < 8; ++c)
#pragma unroll
            for (int r = 0; r < 4; ++r) {
                int row = row_base + g * 16 + q * 4 + r;
                if (row < n) C[(size_t)row * 128 + c * 16 + m] = f32_to_fp8(acc[g][c][r] * dv[g][r]);
            }
}

// ---------------- MFMA GEMM (LDS-staged WT), A bf16 [n,128] -> fp8 h' ----------------
__global__ __launch_bounds__(256) void gemm128_bf16A(const bf16* __restrict__ A,
                                                     const bf16* __restrict__ WT,
                                                     const float* __restrict__ dinv,
                                                     unsigned char* __restrict__ C, int n) {
    __shared__ bf16 wl[128 * WSTRIDE];   // 34 KB
    int t = threadIdx.x;
#pragma unroll
    for (int l = 0; l < 8; ++l) {
        int chunk = t + l * 256;
        int row = chunk >> 4, ch = chunk & 15;
        *(uint4*)&wl[row * WSTRIDE + ch * 8] = *(const uint4*)&WT[row * 128 + ch * 8];
    }
    __syncthreads();
    int wave = t >> 6, lane = t & 63;
    int m = lane & 15, q = lane >> 4;
    int row_base = blockIdx.x * 128 + wave * 32;
    int r0 = min(row_base + m, n - 1);
    int r1 = min(row_base + 16 + m, n - 1);

    f32x4 acc[2][8];
#pragma unroll
    for (int g = 0; g < 2; ++g)
#pragma unroll
        for (int c = 0; c < 8; ++c) acc[g][c] = (f32x4)(0.f);

#pragma unroll
    for (int kt = 0; kt < 4; ++kt) {
        short8 a0 = *(const short8*)&A[(size_t)r0 * 128 + kt * 32 + q * 8];
        short8 a1 = *(const short8*)&A[(size_t)r1 * 128 + kt * 32 + q * 8];
#pragma unroll
        for (int c = 0; c < 8; ++c) {
            short8 bf = *(const short8*)&wl[(c * 16 + m) * WSTRIDE + kt * 32 + q * 8];
            acc[0][c] = __builtin_amdgcn_mfma_f32_16x16x32_bf16(a0, bf, acc[0][c], 0, 0, 0);
            acc[1][c] = __builtin_amdgcn_mfma_f32_16x16x32_bf16(a1, bf, acc[1][c], 0, 0, 0);
        }
    }
    float dv[2][4];
#pragma unroll
    for (int g = 0; g < 2; ++g)
#pragma unroll
        for (int r = 0; r < 4; ++r) {
            int row = row_base + g * 16 + q * 4 + r;
            dv[g][r] = (row < n) ? dinv[row] : 0.f;
        }
#pragma unroll
    for (int g = 0; g < 2; ++g)
#pragma unroll
        for (int c = 0; c < 8; ++c)
#pragma unroll
            for (int r = 0; r < 4; ++r) {
                int row = row_base + g * 16 + q * 4 + r;
                if (row < n) C[(size_t)row * 128 + c * 16 + m] = f32_to_fp8(acc[g][c][r] * dv[g][r]);
            }
}

// ---------------- MFMA GEMM, A bf16 [n,128] x WT4 [32][128] -> bf16 h'4 = h4*dinv ------
// Block 0 also zeroes the bf16 zero row at C[n*32 .. n*32+32) for agg32's tail clamp.
__global__ __launch_bounds__(256) void gemm32_bf16A(const bf16* __restrict__ A,
                                                    const bf16* __restrict__ WT,
                                                    const float* __restrict__ dinv,
                                                    bf16* __restrict__ C, int n) {
    if (blockIdx.x == 0 && threadIdx.x < 32)
        C[(size_t)n * 32 + threadIdx.x] = __float2bfloat16(0.f);
    int wave = threadIdx.x >> 6;
    int lane = threadIdx.x & 63;
    int m = lane & 15;
    int q = lane >> 4;
    int row_base = blockIdx.x * 64 + wave * 16;
    int arow = min(row_base + m, n - 1);

    f32x4 acc[2];
    acc[0] = (f32x4)(0.f);
    acc[1] = (f32x4)(0.f);

#pragma unroll
    for (int kt = 0; kt < 4; ++kt) {
        short8 af = *(const short8*)&A[(size_t)arow * 128 + kt * 32 + q * 8];
#pragma unroll
        for (int c = 0; c < 2; ++c) {
            short8 bf = *(const short8*)&WT[(size_t)(c * 16 + m) * 128 + kt * 32 + q * 8];
            acc[c] = __builtin_amdgcn_mfma_f32_16x16x32_bf16(af, bf, acc[c], 0, 0, 0);
        }
    }
    float dv[4];
#pragma unroll
    for (int r = 0; r < 4; ++r) {
        int row = row_base + q * 4 + r;
        dv[r] = (row < n) ? dinv[row] : 0.f;
    }
#pragma unroll
    for (int c = 0; c < 2; ++c)
#pragma unroll
        for (int r = 0; r < 4; ++r) {
            int row = row_base + q * 4 + r;
            if (row < n) C[(size_t)row * 32 + c * 16 + m] = __float2bfloat16(acc[c][r] * dv[r]);
        }
}

// ---------------- aggregation F=128 fp8: dwordx4 gathers, 8 edges/instr ----------------
// R6-proven structure, full range.
__global__ __launch_bounds__(256) void agg128(const unsigned char* __restrict__ h,
                                              const int2* __restrict__ off2,
                                              const int* __restrict__ edges,
                                              const float* __restrict__ dinv,
                                              const float* __restrict__ bias,
                                              bf16* __restrict__ out, int n) {
    int wid = (blockIdx.x * blockDim.x + threadIdx.x) >> 6;
    if (wid >= n) return;
    int lane = threadIdx.x & 63;
    int g = lane >> 3;                 // edge slot within a gather (0..7)
    int d = lane & 7;                  // 16 B chunk of row
    int l32 = lane & 31;               // position within a 32-edge index window
    const char* hb = (const char*)h;
    unsigned doff = (unsigned)(d << 4);

    int2 rng = off2[wid];
    int i0 = rng.x, i1 = rng.y;
    int deg = i1 - i0;
    int rem = deg & 31;
    int tail = i1 - rem;

    // tail index window: one coalesced load, OOB lanes clamped to zero row h[n]
    int tw = n;
    if (rem) {
        int te = edges[tail + l32];    // slack-allocated
        tw = (l32 < rem) ? te : n;
    }

    f32x2 A[8];
#pragma unroll
    for (int q = 0; q < 8; ++q) A[q] = (f32x2){0.f, 0.f};

    if (g == 0) {                      // self-loop: slot 0 only (8 lanes cover the row)
        uint4 su = *(const uint4*)(hb + (((unsigned)wid << 7) | doff));
        A[0] += __builtin_amdgcn_cvt_pk_f32_fp8((int)su.x, false);
        A[1] += __builtin_amdgcn_cvt_pk_f32_fp8((int)su.x, true);
        A[2] += __builtin_amdgcn_cvt_pk_f32_fp8((int)su.y, false);
        A[3] += __builtin_amdgcn_cvt_pk_f32_fp8((int)su.y, true);
        A[4] += __builtin_amdgcn_cvt_pk_f32_fp8((int)su.z, false);
        A[5] += __builtin_amdgcn_cvt_pk_f32_fp8((int)su.z, true);
        A[6] += __builtin_amdgcn_cvt_pk_f32_fp8((int)su.w, false);
        A[7] += __builtin_amdgcn_cvt_pk_f32_fp8((int)su.w, true);
    }

    int i = i0;
    int ew;
    if (i + 32 <= i1) ew = edges[i + l32];
    while (i + 32 <= i1) {             // full 32-edge chunks: 4 gathers of 8 edges
        int idxs[4];
#pragma unroll
        for (int j = 0; j < 4; ++j) idxs[j] = __shfl(ew, j * 8 + g, 64);
        uint4 uu[4];
#pragma unroll
        for (int j = 0; j < 4; ++j)
            uu[j] = *(const uint4*)(hb + (((unsigned)idxs[j] << 7) | doff));
        int inext = i + 32;
        if (inext + 32 <= i1) ew = edges[inext + l32];   // prefetch next window
#pragma unroll
        for (int j = 0; j < 4; ++j) {
            A[0] += __builtin_amdgcn_cvt_pk_f32_fp8((int)uu[j].x, false);
            A[1] += __builtin_amdgcn_cvt_pk_f32_fp8((int)uu[j].x, true);
            A[2] += __builtin_amdgcn_cvt_pk_f32_fp8((int)uu[j].y, false);
            A[3] += __builtin_amdgcn_cvt_pk_f32_fp8((int)uu[j].y, true);
            A[4] += __builtin_amdgcn_cvt_pk_f32_fp8((int)uu[j].z, false);
            A[5] += __builtin_amdgcn_cvt_pk_f32_fp8((int)uu[j].z, true);
            A[6] += __builtin_amdgcn_cvt_pk_f32_fp8((int)uu[j].w, false);
            A[7] += __builtin_amdgcn_cvt_pk_f32_fp8((int)uu[j].w, true);
        }
        i = inext;
    }
    if (rem) {                         // tail: predicated groups of 8, window pre-clamped
        int njg = (rem + 7) >> 3;      // 1..4
        int idxs[4];
        uint4 uu[4];
#pragma unroll
        for (int j = 0; j < 4; ++j)
            if (j < njg) idxs[j] = __shfl(tw, j * 8 + g, 64);
#pragma unroll
        for (int j = 0; j < 4; ++j)
            if (j < njg) uu[j] = *(const uint4*)(hb + (((unsigned)idxs[j] << 7) | doff));
#pragma unroll
        for (int j = 0; j < 4; ++j) {
            if (j < njg) {
                A[0] += __builtin_amdgcn_cvt_pk_f32_fp8((int)uu[j].x, false);
                A[1] += __builtin_amdgcn_cvt_pk_f32_fp8((int)uu[j].x, true);
                A[2] += __builtin_amdgcn_cvt_pk_f32_fp8((int)uu[j].y, false);
                A[3] += __builtin_amdgcn_cvt_pk_f32_fp8((int)uu[j].y, true);
                A[4] += __builtin_amdgcn_cvt_pk_f32_fp8((int)uu[j].z, false);
                A[5] += __builtin_amdgcn_cvt_pk_f32_fp8((int)uu[j].z, true);
                A[6] += __builtin_amdgcn_cvt_pk_f32_fp8((int)uu[j].w, false);
                A[7] += __builtin_amdgcn_cvt_pk_f32_fp8((int)uu[j].w, true);
            }
        }
    }
    // 3-stage specializing butterfly across the 8 edge slots (g bits at lane 3,4,5)
    bool k0 = (g & 1) != 0, k1 = (g & 2) != 0, k2 = (g & 4) != 0;
    f32x2 B1[4];
#pragma unroll
    for (int q = 0; q < 4; ++q) {
        f32x2 K = k0 ? A[q + 4] : A[q];
        f32x2 S = k0 ? A[q] : A[q + 4];
        f32x2 R; R[0] = __shfl_xor(S[0], 8, 64); R[1] = __shfl_xor(S[1], 8, 64);
        B1[q] = K + R;
    }
    f32x2 B2[2];
#pragma unroll
    for (int q = 0; q < 2; ++q) {
        f32x2 K = k1 ? B1[q + 2] : B1[q];
        f32x2 S = k1 ? B1[q] : B1[q + 2];
        f32x2 R; R[0] = __shfl_xor(S[0], 16, 64); R[1] = __shfl_xor(S[1], 16, 64);
        B2[q] = K + R;
    }
    f32x2 K3 = k2 ? B2[1] : B2[0];
    f32x2 S3 = k2 ? B2[0] : B2[1];
    f32x2 R3; R3[0] = __shfl_xor(S3[0], 32, 64); R3[1] = __shfl_xor(S3[1], 32, 64);
    f32x2 F = K3 + R3;

    int od = d * 8 + (k0 ? 4 : 0) + (k1 ? 2 : 0) + (k2 ? 1 : 0);
    float dl = dinv[wid];
    float2 bv = *(const float2*)&bias[od * 2];
    float a0 = fmaxf(F[0] * dl + bv.x, 0.f);
    float a1 = fmaxf(F[1] * dl + bv.y, 0.f);
    ((unsigned*)out)[(size_t)wid * 64 + od] = pack_bf16x2(a0, a1);
}

// ---------------- aggregation F=32 bf16: window+shuffle + log_softmax -> fp32 ----------
// Half-wave per node. lane5 = (g,d): g = edge slot (0..3), d = 8 B chunk.
// Shuffle sources stay within the node's 32-lane half (halfbase = lane & 32).
__global__ __launch_bounds__(256) void agg32_lsm(const bf16* __restrict__ h,
                                                 const int2* __restrict__ off2,
                                                 const int* __restrict__ edges,
                                                 const float* __restrict__ dinv,
                                                 const float* __restrict__ bias,
                                                 float* __restrict__ out, int n) {
    int idx = blockIdx.x * blockDim.x + threadIdx.x;
    int node = idx >> 5;
    if (node >= n) return;
    int lane = threadIdx.x & 63;
    int halfbase = lane & 32;
    int lane5 = lane & 31;
    int g = lane5 >> 3;        // edge slot 0..3
    int d = lane5 & 7;         // features d*4 .. d*4+3 (8 B = 4 bf16)
    int l16 = lane5 & 15;      // position within a 16-edge index window
    const char* hb = (const char*)h;
    unsigned doff = (unsigned)(d << 3);

    int2 rng = off2[node];
    int i0 = rng.x, i1 = rng.y;
    int deg = i1 - i0;
    int rem = deg & 15;
    int tail = i1 - rem;

    int tw = n;
    if (rem) {
        int te = edges[tail + l16];
        tw = (l16 < rem) ? te : n;    // bf16 zero row at h[n] (written by gemm32)
    }

    f32x2 acc0 = {0.f, 0.f}, acc1 = {0.f, 0.f};
    {   // self-loop: slot 0 only
        uint2 su = *(const uint2*)(hb + (((unsigned)node << 6) | doff));
        if (g) { su.x = 0u; su.y = 0u; }
        float2 f0 = unpack_bf16x2(su.x), f1 = unpack_bf16x2(su.y);
        acc0[0] += f0.x; acc0[1] += f0.y; acc1[0] += f1.x; acc1[1] += f1.y;
    }
    int i = i0;
    int ew;
    if (i + 16 <= i1) ew = edges[i + l16];
    while (i + 16 <= i1) {             // full 16-edge chunks
        int idxs[4];
#pragma unroll
        for (int j = 0; j < 4; ++j) idxs[j] = __shfl(ew, halfbase + j * 4 + g, 64);
        uint2 uu[4];
#pragma unroll
        for (int j = 0; j < 4; ++j)
            uu[j] = *(const uint2*)(hb + (((unsigned)idxs[j] << 6) | doff));
        int inext = i + 16;
        if (inext + 16 <= i1) ew = edges[inext + l16];
#pragma unroll
        for (int j = 0; j < 4; ++j) {
            float2 f0 = unpack_bf16x2(uu[j].x), f1 = unpack_bf16x2(uu[j].y);
            acc0[0] += f0.x; acc0[1] += f0.y; acc1[0] += f1.x; acc1[1] += f1.y;
        }
        i = inext;
    }
    if (rem) {                         // tail: predicated, window pre-clamped
        int njg = (rem + 3) >> 2;      // 1..4
        int idxs[4];
        uint2 uu[4];
#pragma unroll
        for (int j = 0; j < 4; ++j)
            if (j < njg) idxs[j] = __shfl(tw, halfbase + j * 4 + g, 64);
#pragma unroll
        for (int j = 0; j < 4; ++j)
            if (j < njg) uu[j] = *(const uint2*)(hb + (((unsigned)idxs[j] << 6) | doff));
#pragma unroll
        for (int j = 0; j < 4; ++j) {
            if (j < njg) {
                float2 f0 = unpack_bf16x2(uu[j].x), f1 = unpack_bf16x2(uu[j].y);
                acc0[0] += f0.x; acc0[1] += f0.y; acc1[0] += f1.x; acc1[1] += f1.y;
            }
        }
    }
    // reduce across edge slots: g bits are lane bits 3,4 (within the 32-lane half)
    float s0 = acc0[0], s1 = acc0[1], s2 = acc1[0], s3 = acc1[1];
    s0 += __shfl_xor(s0, 8);  s1 += __shfl_xor(s1, 8);
    s2 += __shfl_xor(s2, 8);  s3 += __shfl_xor(s3, 8);
    s0 += __shfl_xor(s0, 16); s1 += __shfl_xor(s1, 16);
    s2 += __shfl_xor(s2, 16); s3 += __shfl_xor(s3, 16);

    float dl = dinv[node];
    float4 bv = *(const float4*)&bias[d * 4];
    float a0 = s0 * dl + bv.x;
    float a1 = s1 * dl + bv.y;
    float a2 = s2 * dl + bv.z;
    float a3 = s3 * dl + bv.w;
    // log_softmax over 32 features: 4 in-lane + across d lanes (bits 0..2)
    float m = fmaxf(fmaxf(a0, a1), fmaxf(a2, a3));
    for (int dd = 1; dd < 8; dd <<= 1) m = fmaxf(m, __shfl_xor(m, dd));
    float e = expf(a0 - m) + expf(a1 - m) + expf(a2 - m) + expf(a3 - m);
    for (int dd = 1; dd < 8; dd <<= 1) e += __shfl_xor(e, dd);
    float lse = m + logf(e);
    if (g == 0)
        *(float4*)&out[(size_t)node * 32 + d * 4] =
            make_float4(a0 - lse, a1 - lse, a2 - lse, a3 - lse);
}

extern "C" void kernel_launch(void* const* d_in, const int* in_sizes, int n_in,
                              void* d_out, int out_size, void* d_ws, size_t ws_size,
                              hipStream_t stream) {
    const float* x  = (const float*)d_in[0];
    const int*   ei = (const int*)d_in[1];
    const float* W1 = (const float*)d_in[2];
    const float* b1 = (const float*)d_in[3];
    const float* W2 = (const float*)d_in[4];
    const float* b2 = (const float*)d_in[5];
    const float* W3 = (const float*)d_in[6];
    const float* b3 = (const float*)d_in[7];
    const float* W4 = (const float*)d_in[8];
    const float* b4 = (const float*)d_in[9];
    float* out = (float*)d_out;

    const int N = NNODES;
    const int E = in_sizes[1] / 2;
    const int nb = (N + 255) / 256;           // 391 buckets

    char* ws = (char*)d_ws;
    size_t o = 0;
    auto alloc = [&](size_t bytes) -> void* {
        void* p = ws + o;
        o += (bytes + 255) & ~(size_t)255;
        return p;
    };
    int*   bcount  = (int*)alloc((size_t)NBMAX * 4);
    int*   boff    = (int*)alloc((size_t)(NBMAX + 1) * 4);
    int*   bcursor = (int*)alloc((size_t)NBMAX * 4);
    int*   done    = (int*)alloc(4);
    int2*  off2    = (int2*)alloc((size_t)N * 8);
    float* dinv    = (float*)alloc((size_t)N * 4);
    int*   part    = (int*)alloc((size_t)E * 8);       // packed ints; region sized E*8 so
                                                       // it can alias gbuf (N*256 B) below
    int*   edges   = (int*)alloc((size_t)(E + 64) * 4); // +64 slack for tail-window reads
    bf16*  wt1     = (bf16*)alloc((size_t)128 * 128 * 2);
    bf16*  wt2     = (bf16*)alloc((size_t)128 * 128 * 2);
    bf16*  wt3     = (bf16*)alloc((size_t)128 * 128 * 2);
    bf16*  wt4     = (bf16*)alloc((size_t)32 * 128 * 2);
    unsigned char* hbuf = (unsigned char*)alloc((size_t)(N + 1) * 128);  // +1: zero row
    bf16*  gbuf    = (bf16*)part;              // part dead after nodes_fill; N*256B == E*8B

    const int* srcv = ei;
    const int* dstv = ei + E;

    int pblocks = (E + CH - 1) / CH;

    // prep_w_all also zeroes bcount/done/fp8-zero-row -> no memsets, runs first
    prep_w_all<<<208, 256, 0, stream>>>(W1, wt1, W2, wt2, W3, wt3, W4, wt4,
                                        bcount, done, (unsigned*)(hbuf + (size_t)N * 128));
    bucket_hist_scan<<<pblocks, 256, 0, stream>>>(dstv, bcount, boff, bcursor, done,
                                                  E, nb, pblocks);
    partition<<<pblocks, 256, 0, stream>>>(srcv, dstv, bcursor, part, E, nb);
    nodes_fill<<<nb, 256, 0, stream>>>(part, boff, dinv, off2, edges, N);

    int gemm128_blocks = (N + 127) / 128;
    int gemm32_blocks = (N + 63) / 64;
    int agg128_blocks = (N + 3) / 4;
    int agg32_blocks = (N * 32 + 255) / 256;

    // Layer 1 (A fp32) -> fp8 h' (pre-scaled by dinv)
    gemm128_f32A<<<gemm128_blocks, 256, 0, stream>>>(x, wt1, dinv, hbuf, N);
    agg128<<<agg128_blocks, 256, 0, stream>>>(hbuf, off2, edges, dinv, b1, gbuf, N);
    // Layer 2
    gemm128_bf16A<<<gemm128_blocks, 256, 0, stream>>>(gbuf, wt2, dinv, hbuf, N);
    agg128<<<agg128_blocks, 256, 0, stream>>>(hbuf, off2, edges, dinv, b2, gbuf, N);
    // Layer 3
    gemm128_bf16A<<<gemm128_blocks, 256, 0, stream>>>(gbuf, wt3, dinv, hbuf, N);
    agg128<<<agg128_blocks, 256, 0, stream>>>(hbuf, off2, edges, dinv, b3, gbuf, N);
    // Layer 4: GEMM to 32 cols (bf16 h'4 - protect final logits), then agg + log_softmax
    gemm32_bf16A<<<gemm32_blocks, 256, 0, stream>>>(gbuf, wt4, dinv, (bf16*)hbuf, N);
    agg32_lsm<<<agg32_blocks, 256, 0, stream>>>((const bf16*)hbuf, off2, edges, dinv, b4, out, N);
}